// Round 13
// baseline (205.743 us; speedup 1.0000x reference)
//
#include <hip/hip_runtime.h>
#include <math.h>

#define BB   16
#define LL   512
#define DD   512
#define HH   8
#define HDIM 64
#define NNEWT 6

typedef unsigned short ushort_t;
typedef __attribute__((ext_vector_type(8))) short short8;
typedef __attribute__((ext_vector_type(4))) float f32x4;

// raw single-instruction transcendentals
__device__ __forceinline__ float hw_log2(float x) { return __builtin_amdgcn_logf(x); }
__device__ __forceinline__ float hw_exp2(float x) { return __builtin_amdgcn_exp2f(x); }
__device__ __forceinline__ float hw_rcp(float x)  { return __builtin_amdgcn_rcpf(x); }

__device__ __forceinline__ ushort_t f2b(float f) {
    unsigned u = __builtin_bit_cast(unsigned, f);
    unsigned r = u + 0x7FFFu + ((u >> 16) & 1u);     // RNE
    return (ushort_t)(r >> 16);
}
__device__ __forceinline__ float b2f(ushort_t u) {
    return __builtin_bit_cast(float, ((unsigned)u) << 16);
}

// ---------------- wave-wide reduction (64 lanes) for ln ----------------
__device__ __forceinline__ float wsum(float v) {
    v += __shfl_xor(v, 1);  v += __shfl_xor(v, 2);  v += __shfl_xor(v, 4);
    v += __shfl_xor(v, 8);  v += __shfl_xor(v, 16); v += __shfl_xor(v, 32);
    return v;
}

// ---------------- DPP butterflies (32-lane groups) ----------------
template<int CTRL>
__device__ __forceinline__ float dpp_mov(float v) {
    return __builtin_bit_cast(float, __builtin_amdgcn_update_dpp(
        0, __builtin_bit_cast(int, v), CTRL, 0xf, 0xf, true));
}
__device__ __forceinline__ float rsum32(float v) {
    v += dpp_mov<0xB1>(v);
    v += dpp_mov<0x4E>(v);
    v += dpp_mov<0x141>(v);
    v += dpp_mov<0x140>(v);
    v += __shfl_xor(v, 16);
    return v;
}
__device__ __forceinline__ float rmax32(float v) {
    v = fmaxf(v, dpp_mov<0xB1>(v));
    v = fmaxf(v, dpp_mov<0x4E>(v));
    v = fmaxf(v, dpp_mov<0x141>(v));
    v = fmaxf(v, dpp_mov<0x140>(v));
    v = fmaxf(v, __shfl_xor(v, 16));
    return v;
}

// ---------------- fp32->bf16 conversions + K^T gather, one kernel ----------------
#define NEC 4194304
#define WNC 262144
// sections: [0, NEC/1024)            : X -> Xb          (float4 -> ushort4)
//           [NEC/1024, +3*WNC/1024)  : Wq|W1|W2 -> Wb
//           [.., +NEC/1024)          : X gather -> Ktb  (transpose, from fp32 X)
__global__ __launch_bounds__(256) void conv_all(
    const float* __restrict__ X, const float* __restrict__ Wq,
    const float* __restrict__ W1, const float* __restrict__ W2,
    ushort_t* __restrict__ Xb, ushort_t* __restrict__ Wb,
    ushort_t* __restrict__ Ktb)
{
    const int SEC1 = NEC / 1024, SEC2 = SEC1 + 3 * WNC / 1024;
    int blk = blockIdx.x;
    if (blk < SEC2) {
        int i = (blk * 256 + threadIdx.x) * 4;
        const float* src; ushort_t* dst; int off, doff;
        if (i < NEC) { src = X; dst = Xb; off = i; doff = i; }
        else {
            int k = i - NEC;
            dst = Wb; doff = k;
            if (k < WNC)          { src = Wq; off = k; }
            else if (k < 2 * WNC) { src = W1; off = k - WNC; }
            else                  { src = W2; off = k - 2 * WNC; }
        }
        float4 v = *(const float4*)&src[off];
        ushort4 o;
        o.x = f2b(v.x); o.y = f2b(v.y); o.z = f2b(v.z); o.w = f2b(v.w);
        *(ushort4*)&dst[doff] = o;
    } else {
        // Ktb[b,h][d][j] = X[b,j,h*64+d]; 4 consecutive j per thread
        int o = ((blk - SEC2) * 256 + threadIdx.x) * 4;
        int j = o & 511;
        int d = (o >> 9) & 63;
        int h = (o >> 15) & 7;
        int b = o >> 18;
        const float* xp = X + ((size_t)(b << 9) + j) * 512 + (h << 6) + d;
        ushort4 ov;
        ov.x = f2b(xp[0]);
        ov.y = f2b(xp[512]);
        ov.z = f2b(xp[1024]);
        ov.w = f2b(xp[1536]);
        *(ushort4*)&Ktb[o] = ov;
    }
}

// ---------------- bf16 MFMA GEMM, 128x64 tile, BK=64 ----------------
__device__ __forceinline__ void gload16(const void* g, void* l) {
    __builtin_amdgcn_global_load_lds(
        (const __attribute__((address_space(1))) unsigned*)g,
        (__attribute__((address_space(3))) unsigned*)l, 16, 0, 0);
}

template<int ACT, bool RES, bool OBF16>
__global__ __launch_bounds__(256) void gemm_mfma(
    const ushort_t* __restrict__ A, const ushort_t* __restrict__ W,
    const float* __restrict__ bias, const ushort_t* __restrict__ resid,
    void* __restrict__ Cout, int M, int N, int K)
{
    __shared__ ushort_t Asw[128 * 64];
    __shared__ ushort_t Bsw[64 * 64];

    const int tid = threadIdx.x;
    const int w = tid >> 6, lane = tid & 63;
    const int wm = w >> 1, wn = w & 1;
    const int bm = blockIdx.y * 128, bn = blockIdx.x * 64;

    const int l3 = lane >> 3, l7 = lane & 7;
    const int srcg = l7 ^ l3;               // pre-swizzled source granule
    const int l15 = lane & 15, hi = lane >> 4;

    f32x4 acc[4][2] = {};

    for (int kt = 0; kt < K; kt += 64) {
        #pragma unroll
        for (int u = 0; u < 4; ++u) {
            int q = w * 4 + u;
            gload16(&A[(size_t)(bm + q * 8 + l3) * K + kt + srcg * 8], &Asw[q * 512]);
        }
        #pragma unroll
        for (int u = 0; u < 2; ++u) {
            int q = w * 2 + u;
            gload16(&W[(size_t)(bn + q * 8 + l3) * K + kt + srcg * 8], &Bsw[q * 512]);
        }
        __syncthreads();

        #pragma unroll
        for (int kk = 0; kk < 2; ++kk) {
            const int s = (kk * 4 + hi) ^ l7;   // swizzled read granule
            short8 a[4], b[2];
            #pragma unroll
            for (int f = 0; f < 4; ++f)
                a[f] = *(const short8*)&Asw[(wm * 64 + f * 16 + l15) * 64 + s * 8];
            #pragma unroll
            for (int f = 0; f < 2; ++f)
                b[f] = *(const short8*)&Bsw[(wn * 32 + f * 16 + l15) * 64 + s * 8];
            #pragma unroll
            for (int i = 0; i < 4; ++i)
                #pragma unroll
                for (int j = 0; j < 2; ++j)
                    acc[i][j] = __builtin_amdgcn_mfma_f32_16x16x32_bf16(
                        a[i], b[j], acc[i][j], 0, 0, 0);
        }
        __syncthreads();
    }

    #pragma unroll
    for (int i = 0; i < 4; ++i) {
        #pragma unroll
        for (int j = 0; j < 2; ++j) {
            #pragma unroll
            for (int r = 0; r < 4; ++r) {
                const int m = bm + wm * 64 + i * 16 + hi * 4 + r;
                const int n = bn + wn * 32 + j * 16 + l15;
                float v = acc[i][j][r] + bias[n];
                if (ACT == 1) v = fmaxf(v, 0.f);
                if (RES) v += b2f(resid[(size_t)m * N + n]);
                if (OBF16) ((ushort_t*)Cout)[(size_t)m * N + n] = f2b(v);
                else       ((float*)Cout)[(size_t)m * N + n] = v;
            }
        }
    }
}

// ---------------- alpha per (b,h), bf16 q ----------------
__global__ void alpha_kernel(const ushort_t* __restrict__ Qb, const float* __restrict__ Wa,
                             const float* __restrict__ ba,
                             float* __restrict__ am1v, float* __restrict__ invv)
{
    int t = threadIdx.x;
    if (t >= BB * HH) return;
    int b = t >> 3, h = t & 7;
    float acc = 0.f;
    #pragma unroll
    for (int d = 0; d < HDIM; ++d)
        acc = fmaf(b2f(Qb[((b << 9) + 511) * 512 + h * 64 + d]), Wa[d], acc);
    acc += ba[0];
    float sig = 1.f / (1.f + expf(-acc));
    float alpha = sig + 1.f;
    const float amin = 1.f + 1e-5f;
    if (alpha < amin) alpha = amin;
    float am1 = alpha - 1.f;
    am1v[t] = am1;
    invv[t] = 1.f / am1;
}

// ---------------- fused attention v12: 8 rows/block, max occupancy ----------------
// LDS ~20 KB -> 8 blocks/CU = 8 waves/SIMD. Phase C is a single pass (8 groups
// x 1 row). MFMA phases keep 16-wide shape; upper 8 B-cols are duplicated
// garbage (qsb[l15&7] / pb[l15&7]) and never written back.
#define SLS 520
__global__ __launch_bounds__(256, 8) void attn_kernel(
    const ushort_t* __restrict__ Qb, const ushort_t* __restrict__ Xb,
    const ushort_t* __restrict__ Ktb,
    const float* __restrict__ mask, const float* __restrict__ am1v,
    const float* __restrict__ invv, ushort_t* __restrict__ ATTb)
{
    __shared__ ushort_t qsb[8][72];    // bf16 Q rows
    __shared__ float SL[8][SLS];       // masked scaled scores -> bf16 P; [row][512]=1/S
    __shared__ float attbuf[8][68];    // mask[512] (phases A-C), att^T staging (D)

    const int bid = ((blockIdx.x & 7) << 10) + (blockIdx.x >> 3);  // XCD swizzle
    const int bh = bid >> 6;           // b*8+h
    const int rg = bid & 63;           // row-group (8 rows)
    const int b = bh >> 3, h = bh & 7;
    const int tid = threadIdx.x;
    const int w = tid >> 6, lane = tid & 63;
    const int l15 = lane & 15, hi = lane >> 4;

    const float am1 = am1v[bh];
    const float inv = invv[bh];
    const float im1c = fmaxf(inv - 1.f, 1e-30f);   // >0 so im1c*log2(0) = -inf -> 0
    const float NEG = -__builtin_inff();
    const float sc = 0.125f * am1;
    float* mlds = &attbuf[0][0];       // 544 floats available

    // ---- phase A: bf16 Q tile + mask -> LDS ----
    if (tid < 128) {
        int idx = tid * 4;             // 0..511
        int rr = idx >> 6, d4 = idx & 63;
        *(ushort4*)&qsb[rr][d4] =
            *(const ushort4*)&Qb[((size_t)((b << 9) + rg * 8 + rr)) * 512 + (h << 6) + d4];
    }
    {
        mlds[tid] = (tid < 511) ? mask[b * 511 + tid] : 0.f;
        int j2 = tid + 256;
        mlds[j2] = (j2 < 511) ? mask[b * 511 + j2] : 0.f;   // last key always masked
    }
    __syncthreads();

    // ---- phase B: S^T = K·Q^T via MFMA; mask+scale applied at write ----
    {
        const ushort_t* xa = Xb + ((size_t)(b << 9)) * 512 + (h << 6);
        #pragma unroll
        for (int jt = 0; jt < 8; ++jt) {
            const int j0 = w * 128 + jt * 16;
            f32x4 acc = {0.f, 0.f, 0.f, 0.f};
            #pragma unroll
            for (int ks = 0; ks < 2; ++ks) {
                short8 a = *(const short8*)&xa[(size_t)(j0 + l15) * 512 + ks * 32 + hi * 8];
                short8 bf = *(const short8*)&qsb[l15 & 7][ks * 32 + hi * 8];
                acc = __builtin_amdgcn_mfma_f32_16x16x32_bf16(a, bf, acc, 0, 0, 0);
            }
            if (l15 < 8) {
                #pragma unroll
                for (int r = 0; r < 4; ++r) {
                    int j = j0 + hi * 4 + r;
                    float mv = mlds[j];
                    SL[l15][j] = (mv == 0.f) ? NEG : acc[r] * sc;
                }
            }
        }
    }
    __syncthreads();

    // ---- phase C: entmax Newton; single pass, 8 x (32-lane group, 1 row) ----
    const int l5 = lane & 31, gg = lane >> 5;
    ushort_t* SLu = (ushort_t*)&SL[0][0];        // row q at SLu + q*1040
    {
        const int row = w * 2 + gg;              // 0..7

        float Xs[16];
        #pragma unroll
        for (int u = 0; u < 8; ++u) {
            float2 sv = *(const float2*)&SL[row][u * 64 + 2 * l5];
            Xs[2*u] = sv.x; Xs[2*u+1] = sv.y;
        }

        float mx = Xs[0];
        #pragma unroll
        for (int e = 1; e < 16; ++e) mx = fmaxf(mx, Xs[e]);
        mx = rmax32(mx);

        float tau = mx - 1.f;      // f(tau) >= 0 here; f convex decreasing
        for (int it = 0; it < NNEWT; ++it) {
            float s0 = 0.f, s1 = 0.f, g0 = 0.f, g1 = 0.f;
            #pragma unroll
            for (int e = 0; e < 16; e += 2) {
                // z <= 1 provably (tau >= mx-1), so [0,1] clamp == max(z,0)
                float za = fminf(fmaxf(Xs[e]     - tau, 0.f), 1.f);
                float zb = fminf(fmaxf(Xs[e + 1] - tau, 0.f), 1.f);
                float da = hw_exp2(im1c * hw_log2(za));   // za^(inv-1); 0 at za=0
                float db = hw_exp2(im1c * hw_log2(zb));
                s0 += da * za; g0 += da;
                s1 += db * zb; g1 += db;
            }
            float S  = rsum32(s0 + s1);
            float Sp = rsum32(g0 + g1);
            tau += (S - 1.f) * hw_rcp(inv * Sp);   // approx step: fine, fixed iters
        }

        // final eval: unnormalized p -> bf16 packed u32; 1/S at fp32 [512]
        float s0 = 0.f, s1 = 0.f;
        #pragma unroll
        for (int u = 0; u < 8; ++u) {
            int j0 = u * 64 + 2 * l5;
            float za = fminf(fmaxf(Xs[2*u]   - tau, 0.f), 1.f);
            float zb = fminf(fmaxf(Xs[2*u+1] - tau, 0.f), 1.f);
            float pa = hw_exp2(inv * hw_log2(za));       // inv>=1: exp2(-inf)=0
            float pb = hw_exp2(inv * hw_log2(zb));
            unsigned pk = (unsigned)f2b(pa) | ((unsigned)f2b(pb) << 16);
            *(unsigned*)&SLu[row * 1040 + j0] = pk;
            s0 += pa; s1 += pb;
        }
        float S = rsum32(s0 + s1);
        if (l5 == 0) SL[row][512] = 1.f / S;
    }
    __syncthreads();   // also separates mask use (attbuf) from phase D writes

    // ---- phase D: att^T = X^T·P^T via MFMA; wave w owns d-tile [w*16,w*16+16) ----
    {
        const ushort_t* ka = Ktb + (size_t)bh * (64 * 512) + (size_t)(w * 16 + l15) * 512;
        const ushort_t* pb = SLu + (l15 & 7) * 1040;
        f32x4 acc0 = {0.f, 0.f, 0.f, 0.f};
        f32x4 acc1 = {0.f, 0.f, 0.f, 0.f};
        #pragma unroll
        for (int ks = 0; ks < 16; ks += 2) {
            short8 a0 = *(const short8*)&ka[ks * 32 + hi * 8];
            short8 b0 = *(const short8*)&pb[ks * 32 + hi * 8];
            short8 a1 = *(const short8*)&ka[(ks + 1) * 32 + hi * 8];
            short8 b1 = *(const short8*)&pb[(ks + 1) * 32 + hi * 8];
            acc0 = __builtin_amdgcn_mfma_f32_16x16x32_bf16(a0, b0, acc0, 0, 0, 0);
            acc1 = __builtin_amdgcn_mfma_f32_16x16x32_bf16(a1, b1, acc1, 0, 0, 0);
        }
        if (l15 < 8) {
            #pragma unroll
            for (int r = 0; r < 4; ++r)
                attbuf[l15][w * 16 + hi * 4 + r] = acc0[r] + acc1[r];
        }
    }
    __syncthreads();

    // ---- store: normalize, write bf16 ATTb (ushort2 = 4B/lane) ----
    {
        int idx = tid * 2;             // 0..510
        int q = idx >> 6, d2 = idx & 63;
        float rn = SL[q][512];
        ushort2 o;
        o.x = f2b(attbuf[q][d2 + 0] * rn);
        o.y = f2b(attbuf[q][d2 + 1] * rn);
        *(ushort2*)&ATTb[((size_t)((b << 9) + rg * 8 + q)) * 512 + (h << 6) + d2] = o;
    }
}

// ---------------- LayerNorm + scatter ----------------
__global__ __launch_bounds__(256) void ln_kernel(const float* __restrict__ Cb,
                                                 const float* __restrict__ g,
                                                 const float* __restrict__ beta,
                                                 float* __restrict__ out)
{
    const int w = threadIdx.x >> 6, lane = threadIdx.x & 63;
    const int row = blockIdx.x * 4 + w;
    const int b = row >> 9, l = row & 511;
    const float* x = Cb + (size_t)row * 512;

    float v[8], s = 0.f;
    #pragma unroll
    for (int k = 0; k < 8; ++k) { v[k] = x[k * 64 + lane]; s += v[k]; }
    s = wsum(s);
    float mu = s * (1.f / 512.f);
    float q = 0.f;
    #pragma unroll
    for (int k = 0; k < 8; ++k) { float d = v[k] - mu; q = fmaf(d, d, q); }
    q = wsum(q);
    float rs = rsqrtf(q * (1.f / 512.f) + 1e-12f);

    float* dst = (l < 511) ? (out + (size_t)(b * 511 + l) * 512)
                           : (out + (size_t)16 * 511 * 512 + (size_t)b * 512);
    #pragma unroll
    for (int k = 0; k < 8; ++k) {
        int d = k * 64 + lane;
        dst[d] = (v[k] - mu) * rs * g[d] + beta[d];
    }
}

// ---------------- launch ----------------
extern "C" void kernel_launch(void* const* d_in, const int* in_sizes, int n_in,
                              void* d_out, int out_size, void* d_ws, size_t ws_size,
                              hipStream_t stream)
{
    const float* X    = (const float*)d_in[0];
    const float* mask = (const float*)d_in[1];
    const float* Wq   = (const float*)d_in[2];
    const float* bq   = (const float*)d_in[3];
    const float* W1   = (const float*)d_in[4];
    const float* b1   = (const float*)d_in[5];
    const float* W2   = (const float*)d_in[6];
    const float* b2   = (const float*)d_in[7];
    const float* lng  = (const float*)d_in[8];
    const float* lnb  = (const float*)d_in[9];
    const float* Wa   = (const float*)d_in[10];
    const float* ba   = (const float*)d_in[11];
    float* out = (float*)d_out;
    float* ws  = (float*)d_ws;

    const size_t NE = (size_t)BB * LL * DD;      // 4194304
    const size_t WN = (size_t)DD * DD;           // 262144
    if (ws_size < (3 * NE + 256) * sizeof(float) + 3 * WN * sizeof(ushort_t)) return;

    float* am1v = ws + 3 * NE;
    float* invv = am1v + 128;
    ushort_t* Wqb = (ushort_t*)(am1v + 256);
    ushort_t* W1b = Wqb + WN;
    ushort_t* W2b = W1b + WN;
    ushort_t* Qbb = (ushort_t*)ws;
    ushort_t* Hhb = Qbb + NE;
    ushort_t* ATTb = (ushort_t*)(ws + NE);
    ushort_t* Xb  = (ushort_t*)(ws + 2 * NE);
    ushort_t* Ktb = Xb + NE;
    float* Cb = ws + 2 * NE;               // Xb/Ktb dead after attn

    const int M = BB * LL;       // 8192
    const int convBlocks = (int)((NE + 3 * WN) / 1024 + NE / 1024);

    conv_all<<<convBlocks, 256, 0, stream>>>(X, Wq, W1, W2, Xb, Wqb, Ktb);
    gemm_mfma<1, false, true><<<dim3(DD / 64, M / 128), 256, 0, stream>>>(
        Xb, Wqb, bq, nullptr, Qbb, M, DD, DD);
    alpha_kernel<<<1, 128, 0, stream>>>(Qbb, Wa, ba, am1v, invv);
    attn_kernel<<<BB * HH * LL / 8, 256, 0, stream>>>(Qbb, Xb, Ktb, mask, am1v, invv, ATTb);
    gemm_mfma<1, false, true><<<dim3(DD / 64, M / 128), 256, 0, stream>>>(
        ATTb, W1b, b1, nullptr, Hhb, M, DD, DD);
    gemm_mfma<0, true, false><<<dim3(DD / 64, M / 128), 256, 0, stream>>>(
        Hhb, W2b, b2, ATTb, Cb, M, DD, DD);
    ln_kernel<<<M / 4, 256, 0, stream>>>(Cb, lng, lnb, out);
}

// Round 15
// 158.846 us; speedup vs baseline: 1.2952x; 1.2952x over previous
//
#include <hip/hip_runtime.h>
#include <math.h>

#define BB   16
#define LL   512
#define DD   512
#define HH   8
#define HDIM 64
#define NNEWT 6

typedef unsigned short ushort_t;
typedef __attribute__((ext_vector_type(8))) short short8;
typedef __attribute__((ext_vector_type(4))) float f32x4;

// raw single-instruction transcendentals
__device__ __forceinline__ float hw_log2(float x) { return __builtin_amdgcn_logf(x); }
__device__ __forceinline__ float hw_exp2(float x) { return __builtin_amdgcn_exp2f(x); }
__device__ __forceinline__ float hw_rcp(float x)  { return __builtin_amdgcn_rcpf(x); }

__device__ __forceinline__ ushort_t f2b(float f) {
    unsigned u = __builtin_bit_cast(unsigned, f);
    unsigned r = u + 0x7FFFu + ((u >> 16) & 1u);     // RNE
    return (ushort_t)(r >> 16);
}
__device__ __forceinline__ float b2f(ushort_t u) {
    return __builtin_bit_cast(float, ((unsigned)u) << 16);
}

// ---------------- wave-wide reduction (64 lanes) ----------------
__device__ __forceinline__ float wsum(float v) {
    v += __shfl_xor(v, 1);  v += __shfl_xor(v, 2);  v += __shfl_xor(v, 4);
    v += __shfl_xor(v, 8);  v += __shfl_xor(v, 16); v += __shfl_xor(v, 32);
    return v;
}

// ---------------- DPP butterflies (32-lane groups) ----------------
template<int CTRL>
__device__ __forceinline__ float dpp_mov(float v) {
    return __builtin_bit_cast(float, __builtin_amdgcn_update_dpp(
        0, __builtin_bit_cast(int, v), CTRL, 0xf, 0xf, true));
}
__device__ __forceinline__ float rsum32(float v) {
    v += dpp_mov<0xB1>(v);
    v += dpp_mov<0x4E>(v);
    v += dpp_mov<0x141>(v);
    v += dpp_mov<0x140>(v);
    v += __shfl_xor(v, 16);
    return v;
}
__device__ __forceinline__ float rmax32(float v) {
    v = fmaxf(v, dpp_mov<0xB1>(v));
    v = fmaxf(v, dpp_mov<0x4E>(v));
    v = fmaxf(v, dpp_mov<0x141>(v));
    v = fmaxf(v, dpp_mov<0x140>(v));
    v = fmaxf(v, __shfl_xor(v, 16));
    return v;
}

// ---------------- fp32->bf16 conversions + K^T gather, one kernel ----------------
#define NEC 4194304
#define WNC 262144
__global__ __launch_bounds__(256) void conv_all(
    const float* __restrict__ X, const float* __restrict__ Wq,
    const float* __restrict__ W1, const float* __restrict__ W2,
    ushort_t* __restrict__ Xb, ushort_t* __restrict__ Wb,
    ushort_t* __restrict__ Ktb)
{
    const int SEC1 = NEC / 1024, SEC2 = SEC1 + 3 * WNC / 1024;
    int blk = blockIdx.x;
    if (blk < SEC2) {
        int i = (blk * 256 + threadIdx.x) * 4;
        const float* src; ushort_t* dst; int off, doff;
        if (i < NEC) { src = X; dst = Xb; off = i; doff = i; }
        else {
            int k = i - NEC;
            dst = Wb; doff = k;
            if (k < WNC)          { src = Wq; off = k; }
            else if (k < 2 * WNC) { src = W1; off = k - WNC; }
            else                  { src = W2; off = k - 2 * WNC; }
        }
        float4 v = *(const float4*)&src[off];
        ushort4 o;
        o.x = f2b(v.x); o.y = f2b(v.y); o.z = f2b(v.z); o.w = f2b(v.w);
        *(ushort4*)&dst[doff] = o;
    } else {
        // Ktb[b,h][d][j] = X[b,j,h*64+d]; 4 consecutive j per thread
        int o = ((blk - SEC2) * 256 + threadIdx.x) * 4;
        int j = o & 511;
        int d = (o >> 9) & 63;
        int h = (o >> 15) & 7;
        int b = o >> 18;
        const float* xp = X + ((size_t)(b << 9) + j) * 512 + (h << 6) + d;
        ushort4 ov;
        ov.x = f2b(xp[0]);
        ov.y = f2b(xp[512]);
        ov.z = f2b(xp[1024]);
        ov.w = f2b(xp[1536]);
        *(ushort4*)&Ktb[o] = ov;
    }
}

// ---------------- bf16 MFMA GEMM, 128x64 tile, BK=64 ----------------
__device__ __forceinline__ void gload16(const void* g, void* l) {
    __builtin_amdgcn_global_load_lds(
        (const __attribute__((address_space(1))) unsigned*)g,
        (__attribute__((address_space(3))) unsigned*)l, 16, 0, 0);
}

template<int ACT, bool RES, bool OBF16>
__global__ __launch_bounds__(256) void gemm_mfma(
    const ushort_t* __restrict__ A, const ushort_t* __restrict__ W,
    const float* __restrict__ bias, const ushort_t* __restrict__ resid,
    void* __restrict__ Cout, int M, int N, int K)
{
    __shared__ ushort_t Asw[128 * 64];
    __shared__ ushort_t Bsw[64 * 64];

    const int tid = threadIdx.x;
    const int w = tid >> 6, lane = tid & 63;
    const int wm = w >> 1, wn = w & 1;
    const int bm = blockIdx.y * 128, bn = blockIdx.x * 64;

    const int l3 = lane >> 3, l7 = lane & 7;
    const int srcg = l7 ^ l3;               // pre-swizzled source granule
    const int l15 = lane & 15, hi = lane >> 4;

    f32x4 acc[4][2] = {};

    for (int kt = 0; kt < K; kt += 64) {
        #pragma unroll
        for (int u = 0; u < 4; ++u) {
            int q = w * 4 + u;
            gload16(&A[(size_t)(bm + q * 8 + l3) * K + kt + srcg * 8], &Asw[q * 512]);
        }
        #pragma unroll
        for (int u = 0; u < 2; ++u) {
            int q = w * 2 + u;
            gload16(&W[(size_t)(bn + q * 8 + l3) * K + kt + srcg * 8], &Bsw[q * 512]);
        }
        __syncthreads();

        #pragma unroll
        for (int kk = 0; kk < 2; ++kk) {
            const int s = (kk * 4 + hi) ^ l7;   // swizzled read granule
            short8 a[4], b[2];
            #pragma unroll
            for (int f = 0; f < 4; ++f)
                a[f] = *(const short8*)&Asw[(wm * 64 + f * 16 + l15) * 64 + s * 8];
            #pragma unroll
            for (int f = 0; f < 2; ++f)
                b[f] = *(const short8*)&Bsw[(wn * 32 + f * 16 + l15) * 64 + s * 8];
            #pragma unroll
            for (int i = 0; i < 4; ++i)
                #pragma unroll
                for (int j = 0; j < 2; ++j)
                    acc[i][j] = __builtin_amdgcn_mfma_f32_16x16x32_bf16(
                        a[i], b[j], acc[i][j], 0, 0, 0);
        }
        __syncthreads();
    }

    #pragma unroll
    for (int i = 0; i < 4; ++i) {
        #pragma unroll
        for (int j = 0; j < 2; ++j) {
            #pragma unroll
            for (int r = 0; r < 4; ++r) {
                const int m = bm + wm * 64 + i * 16 + hi * 4 + r;
                const int n = bn + wn * 32 + j * 16 + l15;
                float v = acc[i][j][r] + bias[n];
                if (ACT == 1) v = fmaxf(v, 0.f);
                if (RES) v += b2f(resid[(size_t)m * N + n]);
                if (OBF16) ((ushort_t*)Cout)[(size_t)m * N + n] = f2b(v);
                else       ((float*)Cout)[(size_t)m * N + n] = v;
            }
        }
    }
}

// ---------------- fused attention v14 = R12 config + folded alpha, NNEWT=6 ----------------
#define SLS 520
__global__ __launch_bounds__(256, 4) void attn_kernel(
    const ushort_t* __restrict__ Qb, const ushort_t* __restrict__ Xb,
    const ushort_t* __restrict__ Ktb,
    const float* __restrict__ mask, const float* __restrict__ Wa,
    const float* __restrict__ ba, ushort_t* __restrict__ ATTb)
{
    __shared__ ushort_t qsb[16][72];   // bf16 Q rows
    __shared__ float SL[16][SLS];      // masked scaled scores -> bf16 P; [row][512]=1/S
    __shared__ float attbuf[16][68];   // mask[512] (phases A-C), att^T staging (D)
    __shared__ float abuf[2];          // am1, inv

    const int bid = ((blockIdx.x & 7) << 9) + (blockIdx.x >> 3);   // XCD swizzle
    const int bh = bid >> 5;
    const int rg = bid & 31;
    const int b = bh >> 3, h = bh & 7;
    const int tid = threadIdx.x;
    const int w = tid >> 6, lane = tid & 63;
    const int l15 = lane & 15, hi = lane >> 4;

    const float NEG = -__builtin_inff();
    float* mlds = &attbuf[0][0];

    // ---- phase A: bf16 Q tile + mask -> LDS; wave 0 computes alpha ----
    {
        int idx = tid * 4;
        int rr = idx >> 6, d4 = idx & 63;
        *(ushort4*)&qsb[rr][d4] =
            *(const ushort4*)&Qb[((size_t)((b << 9) + rg * 16 + rr)) * 512 + (h << 6) + d4];
    }
    #pragma unroll
    for (int u = 0; u < 2; ++u) {
        int j = tid + u * 256;
        mlds[j] = (j < 511) ? mask[b * 511 + j] : 0.f;   // last key always masked
    }
    if (tid < 64) {
        float prod = b2f(Qb[((size_t)((b << 9) + 511)) * 512 + (h << 6) + tid]) * Wa[tid];
        float s = wsum(prod) + ba[0];
        if (tid == 0) {
            float sig = 1.f / (1.f + expf(-s));
            float alpha = sig + 1.f;
            const float amin = 1.f + 1e-5f;
            if (alpha < amin) alpha = amin;
            abuf[0] = alpha - 1.f;
            abuf[1] = 1.f / (alpha - 1.f);
        }
    }
    __syncthreads();

    const float am1 = abuf[0];
    const float inv = abuf[1];
    const float im1c = fmaxf(inv - 1.f, 1e-30f);   // >0 so im1c*log2(0) = -inf -> 0
    const float sc = 0.125f * am1;

    // ---- phase B: S^T = K·Q^T via MFMA; mask+scale applied at write ----
    {
        const ushort_t* xa = Xb + ((size_t)(b << 9)) * 512 + (h << 6);
        #pragma unroll
        for (int jt = 0; jt < 8; ++jt) {
            const int j0 = w * 128 + jt * 16;
            f32x4 acc = {0.f, 0.f, 0.f, 0.f};
            #pragma unroll
            for (int ks = 0; ks < 2; ++ks) {
                short8 a = *(const short8*)&xa[(size_t)(j0 + l15) * 512 + ks * 32 + hi * 8];
                short8 bf = *(const short8*)&qsb[l15][ks * 32 + hi * 8];
                acc = __builtin_amdgcn_mfma_f32_16x16x32_bf16(a, bf, acc, 0, 0, 0);
            }
            #pragma unroll
            for (int r = 0; r < 4; ++r) {
                int j = j0 + hi * 4 + r;
                float mv = mlds[j];                      // 16-lane broadcast
                SL[l15][j] = (mv == 0.f) ? NEG : acc[r] * sc;
            }
        }
    }
    __syncthreads();

    // ---- phase C: entmax Newton; 2 passes x (two 32-lane groups, 1 row each) ----
    const int l5 = lane & 31, gg = lane >> 5;
    ushort_t* SLu = (ushort_t*)&SL[0][0];        // row q at SLu + q*1040

    #pragma unroll
    for (int pp = 0; pp < 2; ++pp) {
        const int row = w * 4 + pp * 2 + gg;

        float Xs[16];
        #pragma unroll
        for (int u = 0; u < 8; ++u) {
            float2 sv = *(const float2*)&SL[row][u * 64 + 2 * l5];
            Xs[2*u] = sv.x; Xs[2*u+1] = sv.y;
        }

        float mx = Xs[0];
        #pragma unroll
        for (int e = 1; e < 16; ++e) mx = fmaxf(mx, Xs[e]);
        mx = rmax32(mx);

        float tau = mx - 1.f;      // f(tau) >= 0 here; f convex decreasing
        for (int it = 0; it < NNEWT; ++it) {
            float s0 = 0.f, s1 = 0.f, g0 = 0.f, g1 = 0.f;
            #pragma unroll
            for (int e = 0; e < 16; e += 2) {
                // z <= 1 provably (tau >= mx-1), so [0,1] clamp == max(z,0)
                float za = fminf(fmaxf(Xs[e]     - tau, 0.f), 1.f);
                float zb = fminf(fmaxf(Xs[e + 1] - tau, 0.f), 1.f);
                float da = hw_exp2(im1c * hw_log2(za));   // za^(inv-1); 0 at za=0
                float db = hw_exp2(im1c * hw_log2(zb));
                s0 += da * za; g0 += da;
                s1 += db * zb; g1 += db;
            }
            float S  = rsum32(s0 + s1);
            float Sp = rsum32(g0 + g1);
            tau += (S - 1.f) * hw_rcp(inv * Sp);   // approx step: fine, fixed iters
        }

        // final eval: unnormalized p -> bf16 packed u32; 1/S at fp32 [512]
        float s0 = 0.f, s1 = 0.f;
        #pragma unroll
        for (int u = 0; u < 8; ++u) {
            int j0 = u * 64 + 2 * l5;
            float za = fminf(fmaxf(Xs[2*u]   - tau, 0.f), 1.f);
            float zb = fminf(fmaxf(Xs[2*u+1] - tau, 0.f), 1.f);
            float pa = hw_exp2(inv * hw_log2(za));       // inv>=1: exp2(-inf)=0
            float pb = hw_exp2(inv * hw_log2(zb));
            unsigned pk = (unsigned)f2b(pa) | ((unsigned)f2b(pb) << 16);
            *(unsigned*)&SLu[row * 1040 + j0] = pk;
            s0 += pa; s1 += pb;
        }
        float S = rsum32(s0 + s1);
        if (l5 == 0) SL[row][512] = 1.f / S;
    }
    __syncthreads();   // also separates mask use (attbuf) from phase D writes

    // ---- phase D: att^T = X^T·P^T via MFMA; wave w owns d-tile [w*16,w*16+16) ----
    {
        const ushort_t* ka = Ktb + (size_t)bh * (64 * 512) + (size_t)(w * 16 + l15) * 512;
        const ushort_t* pb = SLu + l15 * 1040;
        f32x4 acc0 = {0.f, 0.f, 0.f, 0.f};
        f32x4 acc1 = {0.f, 0.f, 0.f, 0.f};
        #pragma unroll
        for (int ks = 0; ks < 16; ks += 2) {
            short8 a0 = *(const short8*)&ka[ks * 32 + hi * 8];
            short8 b0 = *(const short8*)&pb[ks * 32 + hi * 8];
            short8 a1 = *(const short8*)&ka[(ks + 1) * 32 + hi * 8];
            short8 b1 = *(const short8*)&pb[(ks + 1) * 32 + hi * 8];
            acc0 = __builtin_amdgcn_mfma_f32_16x16x32_bf16(a0, b0, acc0, 0, 0, 0);
            acc1 = __builtin_amdgcn_mfma_f32_16x16x32_bf16(a1, b1, acc1, 0, 0, 0);
        }
        #pragma unroll
        for (int r = 0; r < 4; ++r)
            attbuf[l15][w * 16 + hi * 4 + r] = acc0[r] + acc1[r];
    }
    __syncthreads();

    // ---- store: normalize, write bf16 ATTb coalesced (ushort4 = 8B/lane) ----
    {
        int idx = tid * 4;
        int q = idx >> 6, d4 = idx & 63;
        float rn = SL[q][512];
        ushort4 o;
        o.x = f2b(attbuf[q][d4 + 0] * rn);
        o.y = f2b(attbuf[q][d4 + 1] * rn);
        o.z = f2b(attbuf[q][d4 + 2] * rn);
        o.w = f2b(attbuf[q][d4 + 3] * rn);
        *(ushort4*)&ATTb[((size_t)((b << 9) + rg * 16 + q)) * 512 + (h << 6) + d4] = o;
    }
}

// ---------------- LayerNorm + scatter ----------------
__global__ __launch_bounds__(256) void ln_kernel(const float* __restrict__ Cb,
                                                 const float* __restrict__ g,
                                                 const float* __restrict__ beta,
                                                 float* __restrict__ out)
{
    const int w = threadIdx.x >> 6, lane = threadIdx.x & 63;
    const int row = blockIdx.x * 4 + w;
    const int b = row >> 9, l = row & 511;
    const float* x = Cb + (size_t)row * 512;

    float v[8], s = 0.f;
    #pragma unroll
    for (int k = 0; k < 8; ++k) { v[k] = x[k * 64 + lane]; s += v[k]; }
    s = wsum(s);
    float mu = s * (1.f / 512.f);
    float q = 0.f;
    #pragma unroll
    for (int k = 0; k < 8; ++k) { float d = v[k] - mu; q = fmaf(d, d, q); }
    q = wsum(q);
    float rs = rsqrtf(q * (1.f / 512.f) + 1e-12f);

    float* dst = (l < 511) ? (out + (size_t)(b * 511 + l) * 512)
                           : (out + (size_t)16 * 511 * 512 + (size_t)b * 512);
    #pragma unroll
    for (int k = 0; k < 8; ++k) {
        int d = k * 64 + lane;
        dst[d] = (v[k] - mu) * rs * g[d] + beta[d];
    }
}

// ---------------- launch ----------------
extern "C" void kernel_launch(void* const* d_in, const int* in_sizes, int n_in,
                              void* d_out, int out_size, void* d_ws, size_t ws_size,
                              hipStream_t stream)
{
    const float* X    = (const float*)d_in[0];
    const float* mask = (const float*)d_in[1];
    const float* Wq   = (const float*)d_in[2];
    const float* bq   = (const float*)d_in[3];
    const float* W1   = (const float*)d_in[4];
    const float* b1   = (const float*)d_in[5];
    const float* W2   = (const float*)d_in[6];
    const float* b2   = (const float*)d_in[7];
    const float* lng  = (const float*)d_in[8];
    const float* lnb  = (const float*)d_in[9];
    const float* Wa   = (const float*)d_in[10];
    const float* ba   = (const float*)d_in[11];
    float* out = (float*)d_out;
    float* ws  = (float*)d_ws;

    const size_t NE = (size_t)BB * LL * DD;      // 4194304
    const size_t WN = (size_t)DD * DD;           // 262144
    if (ws_size < (3 * NE + 256) * sizeof(float) + 3 * WN * sizeof(ushort_t)) return;

    float* am1v = ws + 3 * NE;                   // (unused slot kept for layout)
    ushort_t* Wqb = (ushort_t*)(am1v + 256);
    ushort_t* W1b = Wqb + WN;
    ushort_t* W2b = W1b + WN;
    ushort_t* Qbb = (ushort_t*)ws;
    ushort_t* Hhb = Qbb + NE;
    ushort_t* ATTb = (ushort_t*)(ws + NE);
    ushort_t* Xb  = (ushort_t*)(ws + 2 * NE);
    ushort_t* Ktb = Xb + NE;
    float* Cb = ws + 2 * NE;               // Xb/Ktb dead after attn

    const int M = BB * LL;       // 8192
    const int convBlocks = (int)((NE + 3 * WN) / 1024 + NE / 1024);

    conv_all<<<convBlocks, 256, 0, stream>>>(X, Wq, W1, W2, Xb, Wqb, Ktb);
    gemm_mfma<1, false, true><<<dim3(DD / 64, M / 128), 256, 0, stream>>>(
        Xb, Wqb, bq, nullptr, Qbb, M, DD, DD);
    attn_kernel<<<BB * HH * LL / 16, 256, 0, stream>>>(Qbb, Xb, Ktb, mask, Wa, ba, ATTb);
    gemm_mfma<1, false, true><<<dim3(DD / 64, M / 128), 256, 0, stream>>>(
        ATTb, W1b, b1, nullptr, Hhb, M, DD, DD);
    gemm_mfma<0, true, false><<<dim3(DD / 64, M / 128), 256, 0, stream>>>(
        Hhb, W2b, b2, ATTb, Cb, M, DD, DD);
    ln_kernel<<<M / 4, 256, 0, stream>>>(Cb, lng, lnb, out);
}

// Round 16
// 154.315 us; speedup vs baseline: 1.3333x; 1.0294x over previous
//
#include <hip/hip_runtime.h>
#include <math.h>

#define BB   16
#define LL   512
#define DD   512
#define HH   8
#define HDIM 64
#define NNEWT 6

typedef unsigned short ushort_t;
typedef __attribute__((ext_vector_type(8))) short short8;
typedef __attribute__((ext_vector_type(4))) float f32x4;

// raw single-instruction transcendentals
__device__ __forceinline__ float hw_log2(float x) { return __builtin_amdgcn_logf(x); }
__device__ __forceinline__ float hw_exp2(float x) { return __builtin_amdgcn_exp2f(x); }
__device__ __forceinline__ float hw_rcp(float x)  { return __builtin_amdgcn_rcpf(x); }

__device__ __forceinline__ ushort_t f2b(float f) {
    unsigned u = __builtin_bit_cast(unsigned, f);
    unsigned r = u + 0x7FFFu + ((u >> 16) & 1u);     // RNE
    return (ushort_t)(r >> 16);
}
__device__ __forceinline__ float b2f(ushort_t u) {
    return __builtin_bit_cast(float, ((unsigned)u) << 16);
}

// ---------------- wave-wide reduction (64 lanes) ----------------
__device__ __forceinline__ float wsum(float v) {
    v += __shfl_xor(v, 1);  v += __shfl_xor(v, 2);  v += __shfl_xor(v, 4);
    v += __shfl_xor(v, 8);  v += __shfl_xor(v, 16); v += __shfl_xor(v, 32);
    return v;
}

// ---------------- DPP butterflies (32-lane groups) ----------------
template<int CTRL>
__device__ __forceinline__ float dpp_mov(float v) {
    return __builtin_bit_cast(float, __builtin_amdgcn_update_dpp(
        0, __builtin_bit_cast(int, v), CTRL, 0xf, 0xf, true));
}
__device__ __forceinline__ float rsum32(float v) {
    v += dpp_mov<0xB1>(v);
    v += dpp_mov<0x4E>(v);
    v += dpp_mov<0x141>(v);
    v += dpp_mov<0x140>(v);
    v += __shfl_xor(v, 16);
    return v;
}
__device__ __forceinline__ float rmax32(float v) {
    v = fmaxf(v, dpp_mov<0xB1>(v));
    v = fmaxf(v, dpp_mov<0x4E>(v));
    v = fmaxf(v, dpp_mov<0x141>(v));
    v = fmaxf(v, dpp_mov<0x140>(v));
    v = fmaxf(v, __shfl_xor(v, 16));
    return v;
}

// ---------------- fp32->bf16 conversions + K^T gather, one kernel ----------------
#define NEC 4194304
#define WNC 262144
__global__ __launch_bounds__(256) void conv_all(
    const float* __restrict__ X, const float* __restrict__ Wq,
    const float* __restrict__ W1, const float* __restrict__ W2,
    ushort_t* __restrict__ Xb, ushort_t* __restrict__ Wb,
    ushort_t* __restrict__ Ktb)
{
    const int SEC1 = NEC / 1024, SEC2 = SEC1 + 3 * WNC / 1024;
    int blk = blockIdx.x;
    if (blk < SEC2) {
        int i = (blk * 256 + threadIdx.x) * 4;
        const float* src; ushort_t* dst; int off, doff;
        if (i < NEC) { src = X; dst = Xb; off = i; doff = i; }
        else {
            int k = i - NEC;
            dst = Wb; doff = k;
            if (k < WNC)          { src = Wq; off = k; }
            else if (k < 2 * WNC) { src = W1; off = k - WNC; }
            else                  { src = W2; off = k - 2 * WNC; }
        }
        float4 v = *(const float4*)&src[off];
        ushort4 o;
        o.x = f2b(v.x); o.y = f2b(v.y); o.z = f2b(v.z); o.w = f2b(v.w);
        *(ushort4*)&dst[doff] = o;
    } else {
        // Ktb[b,h][d][j] = X[b,j,h*64+d]; 4 consecutive j per thread
        int o = ((blk - SEC2) * 256 + threadIdx.x) * 4;
        int j = o & 511;
        int d = (o >> 9) & 63;
        int h = (o >> 15) & 7;
        int b = o >> 18;
        const float* xp = X + ((size_t)(b << 9) + j) * 512 + (h << 6) + d;
        ushort4 ov;
        ov.x = f2b(xp[0]);
        ov.y = f2b(xp[512]);
        ov.z = f2b(xp[1024]);
        ov.w = f2b(xp[1536]);
        *(ushort4*)&Ktb[o] = ov;
    }
}

// ---------------- bf16 MFMA GEMM, 128x64 tile, BK=64 ----------------
__device__ __forceinline__ void gload16(const void* g, void* l) {
    __builtin_amdgcn_global_load_lds(
        (const __attribute__((address_space(1))) unsigned*)g,
        (__attribute__((address_space(3))) unsigned*)l, 16, 0, 0);
}

template<int ACT, bool RES, bool OBF16>
__global__ __launch_bounds__(256) void gemm_mfma(
    const ushort_t* __restrict__ A, const ushort_t* __restrict__ W,
    const float* __restrict__ bias, const ushort_t* __restrict__ resid,
    void* __restrict__ Cout, int M, int N, int K)
{
    __shared__ ushort_t Asw[128 * 64];
    __shared__ ushort_t Bsw[64 * 64];

    const int tid = threadIdx.x;
    const int w = tid >> 6, lane = tid & 63;
    const int wm = w >> 1, wn = w & 1;
    const int bm = blockIdx.y * 128, bn = blockIdx.x * 64;

    const int l3 = lane >> 3, l7 = lane & 7;
    const int srcg = l7 ^ l3;               // pre-swizzled source granule
    const int l15 = lane & 15, hi = lane >> 4;

    f32x4 acc[4][2] = {};

    for (int kt = 0; kt < K; kt += 64) {
        #pragma unroll
        for (int u = 0; u < 4; ++u) {
            int q = w * 4 + u;
            gload16(&A[(size_t)(bm + q * 8 + l3) * K + kt + srcg * 8], &Asw[q * 512]);
        }
        #pragma unroll
        for (int u = 0; u < 2; ++u) {
            int q = w * 2 + u;
            gload16(&W[(size_t)(bn + q * 8 + l3) * K + kt + srcg * 8], &Bsw[q * 512]);
        }
        __syncthreads();

        #pragma unroll
        for (int kk = 0; kk < 2; ++kk) {
            const int s = (kk * 4 + hi) ^ l7;   // swizzled read granule
            short8 a[4], b[2];
            #pragma unroll
            for (int f = 0; f < 4; ++f)
                a[f] = *(const short8*)&Asw[(wm * 64 + f * 16 + l15) * 64 + s * 8];
            #pragma unroll
            for (int f = 0; f < 2; ++f)
                b[f] = *(const short8*)&Bsw[(wn * 32 + f * 16 + l15) * 64 + s * 8];
            #pragma unroll
            for (int i = 0; i < 4; ++i)
                #pragma unroll
                for (int j = 0; j < 2; ++j)
                    acc[i][j] = __builtin_amdgcn_mfma_f32_16x16x32_bf16(
                        a[i], b[j], acc[i][j], 0, 0, 0);
        }
        __syncthreads();
    }

    #pragma unroll
    for (int i = 0; i < 4; ++i) {
        #pragma unroll
        for (int j = 0; j < 2; ++j) {
            #pragma unroll
            for (int r = 0; r < 4; ++r) {
                const int m = bm + wm * 64 + i * 16 + hi * 4 + r;
                const int n = bn + wn * 32 + j * 16 + l15;
                float v = acc[i][j][r] + bias[n];
                if (ACT == 1) v = fmaxf(v, 0.f);
                if (RES) v += b2f(resid[(size_t)m * N + n]);
                if (OBF16) ((ushort_t*)Cout)[(size_t)m * N + n] = f2b(v);
                else       ((float*)Cout)[(size_t)m * N + n] = v;
            }
        }
    }
}

// ---------------- alpha per (b,h), bf16 q (separate tiny kernel) ----------------
__global__ void alpha_kernel(const ushort_t* __restrict__ Qb, const float* __restrict__ Wa,
                             const float* __restrict__ ba,
                             float* __restrict__ am1v, float* __restrict__ invv)
{
    int t = threadIdx.x;
    if (t >= BB * HH) return;
    int b = t >> 3, h = t & 7;
    float acc = 0.f;
    #pragma unroll
    for (int d = 0; d < HDIM; ++d)
        acc = fmaf(b2f(Qb[((b << 9) + 511) * 512 + h * 64 + d]), Wa[d], acc);
    acc += ba[0];
    float sig = 1.f / (1.f + expf(-acc));
    float alpha = sig + 1.f;
    const float amin = 1.f + 1e-5f;
    if (alpha < amin) alpha = amin;
    float am1 = alpha - 1.f;
    am1v[t] = am1;
    invv[t] = 1.f / am1;
}

// ---------------- fused attention (R12 config verbatim) ----------------
#define SLS 520
__global__ __launch_bounds__(256, 4) void attn_kernel(
    const ushort_t* __restrict__ Qb, const ushort_t* __restrict__ Xb,
    const ushort_t* __restrict__ Ktb,
    const float* __restrict__ mask, const float* __restrict__ am1v,
    const float* __restrict__ invv, ushort_t* __restrict__ ATTb)
{
    __shared__ ushort_t qsb[16][72];   // bf16 Q rows
    __shared__ float SL[16][SLS];      // masked scaled scores -> bf16 P; [row][512]=1/S
    __shared__ float attbuf[16][68];   // mask[512] (phases A-C), att^T staging (D)

    const int bid = ((blockIdx.x & 7) << 9) + (blockIdx.x >> 3);   // XCD swizzle
    const int bh = bid >> 5;
    const int rg = bid & 31;
    const int b = bh >> 3, h = bh & 7;
    const int tid = threadIdx.x;
    const int w = tid >> 6, lane = tid & 63;
    const int l15 = lane & 15, hi = lane >> 4;

    const float am1 = am1v[bh];
    const float inv = invv[bh];
    const float im1c = fmaxf(inv - 1.f, 1e-30f);   // >0 so im1c*log2(0) = -inf -> 0
    const float NEG = -__builtin_inff();
    const float sc = 0.125f * am1;
    float* mlds = &attbuf[0][0];

    // ---- phase A: bf16 Q tile + mask -> LDS ----
    {
        int idx = tid * 4;
        int rr = idx >> 6, d4 = idx & 63;
        *(ushort4*)&qsb[rr][d4] =
            *(const ushort4*)&Qb[((size_t)((b << 9) + rg * 16 + rr)) * 512 + (h << 6) + d4];
    }
    #pragma unroll
    for (int u = 0; u < 2; ++u) {
        int j = tid + u * 256;
        mlds[j] = (j < 511) ? mask[b * 511 + j] : 0.f;   // last key always masked
    }
    __syncthreads();

    // ---- phase B: S^T = K·Q^T via MFMA; mask+scale applied at write ----
    {
        const ushort_t* xa = Xb + ((size_t)(b << 9)) * 512 + (h << 6);
        #pragma unroll
        for (int jt = 0; jt < 8; ++jt) {
            const int j0 = w * 128 + jt * 16;
            f32x4 acc = {0.f, 0.f, 0.f, 0.f};
            #pragma unroll
            for (int ks = 0; ks < 2; ++ks) {
                short8 a = *(const short8*)&xa[(size_t)(j0 + l15) * 512 + ks * 32 + hi * 8];
                short8 bf = *(const short8*)&qsb[l15][ks * 32 + hi * 8];
                acc = __builtin_amdgcn_mfma_f32_16x16x32_bf16(a, bf, acc, 0, 0, 0);
            }
            #pragma unroll
            for (int r = 0; r < 4; ++r) {
                int j = j0 + hi * 4 + r;
                float mv = mlds[j];                      // 16-lane broadcast
                SL[l15][j] = (mv == 0.f) ? NEG : acc[r] * sc;
            }
        }
    }
    __syncthreads();

    // ---- phase C: entmax Newton; 2 passes x (two 32-lane groups, 1 row each) ----
    const int l5 = lane & 31, gg = lane >> 5;
    ushort_t* SLu = (ushort_t*)&SL[0][0];        // row q at SLu + q*1040

    #pragma unroll
    for (int pp = 0; pp < 2; ++pp) {
        const int row = w * 4 + pp * 2 + gg;

        float Xs[16];
        #pragma unroll
        for (int u = 0; u < 8; ++u) {
            float2 sv = *(const float2*)&SL[row][u * 64 + 2 * l5];
            Xs[2*u] = sv.x; Xs[2*u+1] = sv.y;
        }

        float mx = Xs[0];
        #pragma unroll
        for (int e = 1; e < 16; ++e) mx = fmaxf(mx, Xs[e]);
        mx = rmax32(mx);

        float tau = mx - 1.f;      // f(tau) >= 0 here; f convex decreasing
        for (int it = 0; it < NNEWT; ++it) {
            float s0 = 0.f, s1 = 0.f, g0 = 0.f, g1 = 0.f;
            #pragma unroll
            for (int e = 0; e < 16; e += 2) {
                // z <= 1 provably (tau >= mx-1), so [0,1] clamp == max(z,0)
                float za = fminf(fmaxf(Xs[e]     - tau, 0.f), 1.f);
                float zb = fminf(fmaxf(Xs[e + 1] - tau, 0.f), 1.f);
                float da = hw_exp2(im1c * hw_log2(za));   // za^(inv-1); 0 at za=0
                float db = hw_exp2(im1c * hw_log2(zb));
                s0 += da * za; g0 += da;
                s1 += db * zb; g1 += db;
            }
            float S  = rsum32(s0 + s1);
            float Sp = rsum32(g0 + g1);
            tau += (S - 1.f) * hw_rcp(inv * Sp);   // approx step: fine, fixed iters
        }

        // final eval: unnormalized p -> bf16 packed u32; 1/S at fp32 [512]
        float s0 = 0.f, s1 = 0.f;
        #pragma unroll
        for (int u = 0; u < 8; ++u) {
            int j0 = u * 64 + 2 * l5;
            float za = fminf(fmaxf(Xs[2*u]   - tau, 0.f), 1.f);
            float zb = fminf(fmaxf(Xs[2*u+1] - tau, 0.f), 1.f);
            float pa = hw_exp2(inv * hw_log2(za));       // inv>=1: exp2(-inf)=0
            float pb = hw_exp2(inv * hw_log2(zb));
            unsigned pk = (unsigned)f2b(pa) | ((unsigned)f2b(pb) << 16);
            *(unsigned*)&SLu[row * 1040 + j0] = pk;
            s0 += pa; s1 += pb;
        }
        float S = rsum32(s0 + s1);
        if (l5 == 0) SL[row][512] = 1.f / S;
    }
    __syncthreads();   // also separates mask use (attbuf) from phase D writes

    // ---- phase D: att^T = X^T·P^T via MFMA; wave w owns d-tile [w*16,w*16+16) ----
    {
        const ushort_t* ka = Ktb + (size_t)bh * (64 * 512) + (size_t)(w * 16 + l15) * 512;
        const ushort_t* pb = SLu + l15 * 1040;
        f32x4 acc0 = {0.f, 0.f, 0.f, 0.f};
        f32x4 acc1 = {0.f, 0.f, 0.f, 0.f};
        #pragma unroll
        for (int ks = 0; ks < 16; ks += 2) {
            short8 a0 = *(const short8*)&ka[ks * 32 + hi * 8];
            short8 b0 = *(const short8*)&pb[ks * 32 + hi * 8];
            short8 a1 = *(const short8*)&ka[(ks + 1) * 32 + hi * 8];
            short8 b1 = *(const short8*)&pb[(ks + 1) * 32 + hi * 8];
            acc0 = __builtin_amdgcn_mfma_f32_16x16x32_bf16(a0, b0, acc0, 0, 0, 0);
            acc1 = __builtin_amdgcn_mfma_f32_16x16x32_bf16(a1, b1, acc1, 0, 0, 0);
        }
        #pragma unroll
        for (int r = 0; r < 4; ++r)
            attbuf[l15][w * 16 + hi * 4 + r] = acc0[r] + acc1[r];
    }
    __syncthreads();

    // ---- store: normalize, write bf16 ATTb coalesced (ushort4 = 8B/lane) ----
    {
        int idx = tid * 4;
        int q = idx >> 6, d4 = idx & 63;
        float rn = SL[q][512];
        ushort4 o;
        o.x = f2b(attbuf[q][d4 + 0] * rn);
        o.y = f2b(attbuf[q][d4 + 1] * rn);
        o.z = f2b(attbuf[q][d4 + 2] * rn);
        o.w = f2b(attbuf[q][d4 + 3] * rn);
        *(ushort4*)&ATTb[((size_t)((b << 9) + rg * 16 + q)) * 512 + (h << 6) + d4] = o;
    }
}

// ---------------- LayerNorm + scatter ----------------
__global__ __launch_bounds__(256) void ln_kernel(const float* __restrict__ Cb,
                                                 const float* __restrict__ g,
                                                 const float* __restrict__ beta,
                                                 float* __restrict__ out)
{
    const int w = threadIdx.x >> 6, lane = threadIdx.x & 63;
    const int row = blockIdx.x * 4 + w;
    const int b = row >> 9, l = row & 511;
    const float* x = Cb + (size_t)row * 512;

    float v[8], s = 0.f;
    #pragma unroll
    for (int k = 0; k < 8; ++k) { v[k] = x[k * 64 + lane]; s += v[k]; }
    s = wsum(s);
    float mu = s * (1.f / 512.f);
    float q = 0.f;
    #pragma unroll
    for (int k = 0; k < 8; ++k) { float d = v[k] - mu; q = fmaf(d, d, q); }
    q = wsum(q);
    float rs = rsqrtf(q * (1.f / 512.f) + 1e-12f);

    float* dst = (l < 511) ? (out + (size_t)(b * 511 + l) * 512)
                           : (out + (size_t)16 * 511 * 512 + (size_t)b * 512);
    #pragma unroll
    for (int k = 0; k < 8; ++k) {
        int d = k * 64 + lane;
        dst[d] = (v[k] - mu) * rs * g[d] + beta[d];
    }
}

// ---------------- launch ----------------
extern "C" void kernel_launch(void* const* d_in, const int* in_sizes, int n_in,
                              void* d_out, int out_size, void* d_ws, size_t ws_size,
                              hipStream_t stream)
{
    const float* X    = (const float*)d_in[0];
    const float* mask = (const float*)d_in[1];
    const float* Wq   = (const float*)d_in[2];
    const float* bq   = (const float*)d_in[3];
    const float* W1   = (const float*)d_in[4];
    const float* b1   = (const float*)d_in[5];
    const float* W2   = (const float*)d_in[6];
    const float* b2   = (const float*)d_in[7];
    const float* lng  = (const float*)d_in[8];
    const float* lnb  = (const float*)d_in[9];
    const float* Wa   = (const float*)d_in[10];
    const float* ba   = (const float*)d_in[11];
    float* out = (float*)d_out;
    float* ws  = (float*)d_ws;

    const size_t NE = (size_t)BB * LL * DD;      // 4194304
    const size_t WN = (size_t)DD * DD;           // 262144
    if (ws_size < (3 * NE + 256) * sizeof(float) + 3 * WN * sizeof(ushort_t)) return;

    float* am1v = ws + 3 * NE;
    float* invv = am1v + 128;
    ushort_t* Wqb = (ushort_t*)(am1v + 256);
    ushort_t* W1b = Wqb + WN;
    ushort_t* W2b = W1b + WN;
    ushort_t* Qbb = (ushort_t*)ws;
    ushort_t* Hhb = Qbb + NE;
    ushort_t* ATTb = (ushort_t*)(ws + NE);
    ushort_t* Xb  = (ushort_t*)(ws + 2 * NE);
    ushort_t* Ktb = Xb + NE;
    float* Cb = ws + 2 * NE;               // Xb/Ktb dead after attn

    const int M = BB * LL;       // 8192
    const int convBlocks = (int)((NE + 3 * WN) / 1024 + NE / 1024);

    conv_all<<<convBlocks, 256, 0, stream>>>(X, Wq, W1, W2, Xb, Wqb, Ktb);
    gemm_mfma<1, false, true><<<dim3(DD / 64, M / 128), 256, 0, stream>>>(
        Xb, Wqb, bq, nullptr, Qbb, M, DD, DD);
    alpha_kernel<<<1, 128, 0, stream>>>(Qbb, Wa, ba, am1v, invv);
    attn_kernel<<<BB * HH * LL / 16, 256, 0, stream>>>(Qbb, Xb, Ktb, mask, am1v, invv, ATTb);
    gemm_mfma<1, false, true><<<dim3(DD / 64, M / 128), 256, 0, stream>>>(
        ATTb, W1b, b1, nullptr, Hhb, M, DD, DD);
    gemm_mfma<0, true, false><<<dim3(DD / 64, M / 128), 256, 0, stream>>>(
        Hhb, W2b, b2, ATTb, Cb, M, DD, DD);
    ln_kernel<<<M / 4, 256, 0, stream>>>(Cb, lng, lnb, out);
}